// Round 5
// baseline (239.670 us; speedup 1.0000x reference)
//
#include <hip/hip_runtime.h>

typedef __bf16 bf16;
typedef __bf16 bf16x4 __attribute__((ext_vector_type(4)));
typedef __bf16 bf16x8 __attribute__((ext_vector_type(8)));
typedef float f32x4 __attribute__((ext_vector_type(4)));
typedef float f32x16 __attribute__((ext_vector_type(16)));

#define DIMD 1024
#define NHEAD 16
#define HDIM 64
#define BATCH 2
#define SEQ 2048
#define MTOT (BATCH*SEQ)   // 4096

#define EXP2F(x) __builtin_amdgcn_exp2f(x)

// ---- memory plan (total ws use = 16 MB) ----
// d_out: [0,8MB) Qb bf16 (pre-scaled 0.125*log2e); [8,16MB) Kb   (dead after attn -> out)
// d_ws:  [0,8MB) xb bf16 -> dead after QKV GEMM, then Ob
//        [8,16MB) Vt bf16 -> dead after attn, then wprojb bf16 (2MB)
#define OFF_XB (0ull)
#define OFF_OB (0ull)
#define OFF_VT (8ull<<20)
#define OFF_WP (8ull<<20)

__device__ __forceinline__ void g2l16(const void* g, void* l) {
  __builtin_amdgcn_global_load_lds(
      (const __attribute__((address_space(1))) void*)g,
      (__attribute__((address_space(3))) void*)l,
      16, 0, 0);
}

__device__ __forceinline__ bf16x8 cvt8(float4 a, float4 b) {
  bf16x8 r = { (bf16)a.x, (bf16)a.y, (bf16)a.z, (bf16)a.w,
               (bf16)b.x, (bf16)b.y, (bf16)b.z, (bf16)b.w };
  return r;
}

// ---------------- fp32 -> bf16 conversion ----------------
__global__ __launch_bounds__(256) void cvt_kernel(const float* __restrict__ in,
                                                  bf16* __restrict__ out, int n4) {
  int i = blockIdx.x * blockDim.x + threadIdx.x;
  if (i < n4) {
    float4 v = ((const float4*)in)[i];
    bf16x4 o = { (bf16)v.x, (bf16)v.y, (bf16)v.z, (bf16)v.w };
    ((bf16x4*)out)[i] = o;
  }
}

// ---------------- QKV GEMM (R9/R10 inner loop; + XCD L2-blocking swizzle) ---
// Swizzle: each XCD owns a 3-Ntile x 32-Mtile stripe -> its W working set is
// 3 x 512KB = 1.5MB (fits 4MB L2); consecutive blocks within the stripe share
// the A-panel. Pure index remap; inner loop untouched.
__global__ __launch_bounds__(256, 3) void gemm_qkv(
    const bf16* __restrict__ A, const float* __restrict__ W,
    const float* __restrict__ bias,
    bf16* __restrict__ Qb, bf16* __restrict__ Kb, bf16* __restrict__ Vt)
{
  __shared__ bf16 lA[2][128 * 32];
  __shared__ bf16 lB[2][128 * 32];
  const int tid = threadIdx.x;
  const int wave = tid >> 6, lane = tid & 63;
  const int l15 = lane & 15, quad = lane >> 4;
  const int wm = wave >> 1, wn = wave & 1;

  const int lin = blockIdx.y * 24 + blockIdx.x;   // 768 blocks, 768%8==0
  const int xcd = lin & 7, idx = lin >> 3;        // 96 blocks per XCD
  const int tn_i = xcd * 3 + idx % 3;             // 3 N-tiles per XCD stripe
  const int tm_i = idx / 3;                       // 32 M-tiles
  const int tm = tm_i * 128, tn = tn_i * 128;

  f32x4 acc[4][4] = {};

  const int srow = tid >> 2, sch = (tid & 3) * 8;
  const bf16*  ga = &A[(size_t)(tm + srow) * DIMD + sch];
  const float* gb = &W[(size_t)(tn + srow) * DIMD + sch];

  g2l16(ga,                     &lA[0][wave * 512]);
  g2l16(ga + (size_t)64 * DIMD, &lA[0][2048 + wave * 512]);
  float4 bv0 = ((const float4*)gb)[0], bv1 = ((const float4*)gb)[1];
  float4 bv2 = ((const float4*)(gb + (size_t)64 * DIMD))[0],
         bv3 = ((const float4*)(gb + (size_t)64 * DIMD))[1];

  for (int kt = 0; kt < 32; kt++) {
    bf16* sB = lB[kt & 1];
    *(bf16x8*)&sB[srow * 32 + sch]        = cvt8(bv0, bv1);
    *(bf16x8*)&sB[(64 + srow) * 32 + sch] = cvt8(bv2, bv3);
    __syncthreads();

    if (kt < 31) {
      const int kn = (kt + 1) * 32;
      bf16* nA = lA[(kt + 1) & 1];
      g2l16(ga + kn,                     &nA[wave * 512]);
      g2l16(ga + kn + (size_t)64 * DIMD, &nA[2048 + wave * 512]);
      const float* gbn = gb + kn;
      bv0 = ((const float4*)gbn)[0]; bv1 = ((const float4*)gbn)[1];
      bv2 = ((const float4*)(gbn + (size_t)64 * DIMD))[0];
      bv3 = ((const float4*)(gbn + (size_t)64 * DIMD))[1];
    }

    const bf16* sA = lA[kt & 1];
    bf16x8 af[4], bfr[4];
#pragma unroll
    for (int i = 0; i < 4; i++)
      af[i] = *(const bf16x8*)&sA[(wm * 64 + i * 16 + l15) * 32 + quad * 8];
#pragma unroll
    for (int i = 0; i < 4; i++)
      bfr[i] = *(const bf16x8*)&sB[(wn * 64 + i * 16 + l15) * 32 + quad * 8];
#pragma unroll
    for (int i = 0; i < 4; i++)
#pragma unroll
      for (int j = 0; j < 4; j++)
        acc[i][j] = __builtin_amdgcn_mfma_f32_16x16x32_bf16(af[i], bfr[j], acc[i][j], 0, 0, 0);
  }

  const int sel = tn >> 10;  // 0=Q 1=K 2=V
#pragma unroll
  for (int j = 0; j < 4; j++) {
    const int n = tn + wn * 64 + j * 16 + l15;
    const float bv = bias[n];
    const int d = n & 1023, h = d >> 6, hd = d & 63;
#pragma unroll
    for (int i = 0; i < 4; i++) {
      const int mbase = tm + wm * 64 + i * 16 + quad * 4;
      const int b = mbase >> 11, s0 = mbase & 2047;
      const int bh = b * NHEAD + h;
      if (sel == 2) {
        bf16x4 vv = { (bf16)(acc[i][j][0] + bv), (bf16)(acc[i][j][1] + bv),
                      (bf16)(acc[i][j][2] + bv), (bf16)(acc[i][j][3] + bv) };
        *(bf16x4*)&Vt[((size_t)bh * HDIM + hd) * SEQ + s0] = vv;
      } else {
#pragma unroll
        for (int r = 0; r < 4; r++) {
          float v = acc[i][j][r] + bv;
          if (sel == 0)
            Qb[((size_t)bh * SEQ + s0 + r) * HDIM + hd] = (bf16)(v * 0.18033688f); // 0.125*log2e
          else
            Kb[((size_t)bh * SEQ + s0 + r) * HDIM + hd] = (bf16)v;
        }
      }
    }
  }
}

// ---------------- proj GEMM v2: both operands async via global_load_lds ----
__global__ __launch_bounds__(256, 2) void gemm_proj(
    const bf16* __restrict__ A, const bf16* __restrict__ Bt,
    const float* __restrict__ bias, float* __restrict__ out)
{
  __shared__ bf16 lA[2][64 * 32];
  __shared__ bf16 lB[2][128 * 32];
  const int tid = threadIdx.x;
  const int wave = tid >> 6, lane = tid & 63;
  const int l15 = lane & 15, quad = lane >> 4;
  const int tm = blockIdx.y * 64, tn = blockIdx.x * 128;

  f32x4 acc[4][2] = {};

  const int srow = tid >> 2, sch = (tid & 3) * 8;
  const bf16* ga = &A[(size_t)(tm + srow) * DIMD + sch];
  const bf16* gb = &Bt[(size_t)(tn + srow) * DIMD + sch];

  g2l16(ga,                     &lA[0][wave * 512]);
  g2l16(gb,                     &lB[0][wave * 512]);
  g2l16(gb + (size_t)64 * DIMD, &lB[0][2048 + wave * 512]);

  for (int kt = 0; kt < 32; kt++) {
    __syncthreads();

    if (kt < 31) {
      const int kn = (kt + 1) * 32;
      bf16* nA = lA[(kt + 1) & 1];
      bf16* nB = lB[(kt + 1) & 1];
      g2l16(ga + kn,                     &nA[wave * 512]);
      g2l16(gb + kn,                     &nB[wave * 512]);
      g2l16(gb + kn + (size_t)64 * DIMD, &nB[2048 + wave * 512]);
    }

    const bf16* sA = lA[kt & 1];
    const bf16* sB = lB[kt & 1];
    bf16x8 af[4], bfr[2];
#pragma unroll
    for (int i = 0; i < 4; i++)
      af[i] = *(const bf16x8*)&sA[(i * 16 + l15) * 32 + quad * 8];
#pragma unroll
    for (int j = 0; j < 2; j++)
      bfr[j] = *(const bf16x8*)&sB[(wave * 32 + j * 16 + l15) * 32 + quad * 8];
#pragma unroll
    for (int i = 0; i < 4; i++)
#pragma unroll
      for (int j = 0; j < 2; j++)
        acc[i][j] = __builtin_amdgcn_mfma_f32_16x16x32_bf16(af[i], bfr[j], acc[i][j], 0, 0, 0);
  }

#pragma unroll
  for (int j = 0; j < 2; j++) {
    const int n = tn + wave * 32 + j * 16 + l15;
    const float bv = bias[n];
#pragma unroll
    for (int i = 0; i < 4; i++) {
      const int mbase = tm + i * 16 + quad * 4;
#pragma unroll
      for (int r = 0; r < 4; r++)
        out[(size_t)(mbase + r) * DIMD + n] = acc[i][j][r] + bv;
    }
  }
}

// ---------------- flash attention v11: KVBLK=128, two in-iteration sub-steps
// v10 counters: MFMA 23% + VALU 41% + DS ~25% ~= 90% -> pipes used serially;
// per-iter barrier phase-locks all 4 waves. Occupancy is work-capped (2048
// waves = 2/SIMD), so the fix is intra-iteration overlap + barrier amortize:
//  * 128 K-rows per barrier (16 iters, was 32).
//  * schedule QK_A -> QK_B || SM_A -> PV_A || SM_B -> PV_B: VALU softmax of
//    one sub-step overlaps the MFMA cluster of the other.
//  * PV in-iteration (reads only buf[kt&1]) -> removes v6/v10's latent
//    stage-vs-deferred-PV race AND the pf cross-iteration carry.
//  * LDS 71680B -> max 2 blocks/CU: forces compiler to target 2 waves/SIMD
//    (256 VGPR budget), guarding against v9's 4-block spill heuristic.
// All fragment layouts / staging patterns / pack-exchange identical to v10.
#define KSTR 72
#define VSTR 136
__global__ __launch_bounds__(256, 2) void attn_kernel(
    const bf16* __restrict__ Qb, const bf16* __restrict__ Kb,
    const bf16* __restrict__ Vt, bf16* __restrict__ Ob)
{
  __shared__ bf16 lK[2][128 * KSTR];   // 2 x 18432 B
  __shared__ bf16 lV[2][64 * VSTR];    // 2 x 17408 B   (total 71680 B)

  const int tid = threadIdx.x;
  const int wave = tid >> 6, lane = tid & 63;
  const int l31 = lane & 31, h = lane >> 5;
  const int xcd = blockIdx.x & 7, grp = blockIdx.x >> 3;
  const int bh = xcd + 8 * (grp & 3);
  const int qt = grp >> 2;

  const int qrow = qt * 128 + wave * 32 + l31;
  const bf16* qp = Qb + ((size_t)bh * SEQ + qrow) * HDIM + h * 8;
  bf16x8 qf[4];
#pragma unroll
  for (int c = 0; c < 4; c++) qf[c] = *(const bf16x8*)(qp + c * 16);

  const int srow = tid >> 3;            // 0..31
  const int sch = (tid & 7) * 8;        // bf16 elem offset in 64
  const bf16* kg = Kb + ((size_t)bh * SEQ + srow) * HDIM + sch;
  const bf16* vg = Vt + ((size_t)bh * HDIM + srow) * SEQ + sch;

  uint4 kr[4], vr[4];
#pragma unroll
  for (int i = 0; i < 4; i++)
    kr[i] = *(const uint4*)(kg + (size_t)(32 * i) * HDIM);
#pragma unroll
  for (int i = 0; i < 2; i++)
#pragma unroll
    for (int j = 0; j < 2; j++)
      vr[2 * i + j] = *(const uint4*)(vg + (size_t)(32 * i) * SEQ + j * 64);

  f32x16 o0 = {}, o1 = {};
  float mrow = -1e30f, lrow = 0.f;

  for (int kt = 0; kt < SEQ / 128; kt++) {
    bf16* sK = lK[kt & 1];
    bf16* sV = lV[kt & 1];
#pragma unroll
    for (int i = 0; i < 4; i++)
      *(uint4*)&sK[(srow + 32 * i) * KSTR + sch] = kr[i];
#pragma unroll
    for (int i = 0; i < 2; i++)
#pragma unroll
      for (int j = 0; j < 2; j++)
        *(uint4*)&sV[(srow + 32 * i) * VSTR + j * 64 + sch] = vr[2 * i + j];
    __syncthreads();

    if (kt < SEQ / 128 - 1) {
      const size_t koff = (size_t)(kt + 1) * 128;
#pragma unroll
      for (int i = 0; i < 4; i++)
        kr[i] = *(const uint4*)(kg + (koff + 32 * i) * HDIM);
#pragma unroll
      for (int i = 0; i < 2; i++)
#pragma unroll
        for (int j = 0; j < 2; j++)
          vr[2 * i + j] = *(const uint4*)(vg + (size_t)(32 * i) * SEQ + koff + j * 64);
    }

    // ---- QK for both sub-steps (B's MFMAs overlap A's softmax below) ----
    f32x16 s0 = {}, s1 = {}, s2 = {}, s3 = {};
#pragma unroll
    for (int c = 0; c < 4; c++) {
      bf16x8 k0 = *(const bf16x8*)&sK[(l31)      * KSTR + c * 16 + h * 8];
      bf16x8 k1 = *(const bf16x8*)&sK[(32 + l31) * KSTR + c * 16 + h * 8];
      s0 = __builtin_amdgcn_mfma_f32_32x32x16_bf16(k0, qf[c], s0, 0, 0, 0);
      s1 = __builtin_amdgcn_mfma_f32_32x32x16_bf16(k1, qf[c], s1, 0, 0, 0);
    }
#pragma unroll
    for (int c = 0; c < 4; c++) {
      bf16x8 k2 = *(const bf16x8*)&sK[(64 + l31) * KSTR + c * 16 + h * 8];
      bf16x8 k3 = *(const bf16x8*)&sK[(96 + l31) * KSTR + c * 16 + h * 8];
      s2 = __builtin_amdgcn_mfma_f32_32x32x16_bf16(k2, qf[c], s2, 0, 0, 0);
      s3 = __builtin_amdgcn_mfma_f32_32x32x16_bf16(k3, qf[c], s3, 0, 0, 0);
    }

    // ---- sub-step A: softmax(s0,s1) + pack + PV (V cols 0..63) ----
    {
      float mx = -1e30f;
#pragma unroll
      for (int r = 0; r < 16; r++) { mx = fmaxf(mx, s0[r]); mx = fmaxf(mx, s1[r]); }
      mx = fmaxf(mx, __shfl_xor(mx, 32, 64));
      const float nm = fmaxf(mrow, mx);
      const float alpha = EXP2F(mrow - nm);
      mrow = nm;
      float rs = 0.f;
#pragma unroll
      for (int r = 0; r < 16; r++) {
        const float p0 = EXP2F(s0[r] - nm);
        const float p1 = EXP2F(s1[r] - nm);
        s0[r] = p0; s1[r] = p1;
        rs += p0 + p1;
      }
      rs += __shfl_xor(rs, 32, 64);
      lrow = lrow * alpha + rs;
#pragma unroll
      for (int r = 0; r < 16; r++) { o0[r] *= alpha; o1[r] *= alpha; }

      bf16x8 pfA[4];
#pragma unroll
      for (int g = 0; g < 2; g++) {
        const f32x16& sg = (g == 0) ? s0 : s1;
#pragma unroll
        for (int cp = 0; cp < 2; cp++) {
          bf16x4 pk0 = { (bf16)sg[8 * cp + 0], (bf16)sg[8 * cp + 1],
                         (bf16)sg[8 * cp + 2], (bf16)sg[8 * cp + 3] };
          bf16x4 pk1 = { (bf16)sg[8 * cp + 4], (bf16)sg[8 * cp + 5],
                         (bf16)sg[8 * cp + 6], (bf16)sg[8 * cp + 7] };
          uint2 w0 = *(uint2*)&pk0;
          uint2 w1 = *(uint2*)&pk1;
          unsigned send0 = h ? w0.x : w1.x;
          unsigned send1 = h ? w0.y : w1.y;
          unsigned recv0 = __shfl_xor(send0, 32, 64);
          unsigned recv1 = __shfl_xor(send1, 32, 64);
          union { unsigned u[4]; bf16x8 v; } f;
          f.u[0] = h ? recv0 : w0.x;
          f.u[1] = h ? recv1 : w0.y;
          f.u[2] = h ? w1.x : recv0;
          f.u[3] = h ? w1.y : recv1;
          pfA[2 * g + cp] = f.v;
        }
      }
#pragma unroll
      for (int c = 0; c < 4; c++) {
        bf16x8 v0 = *(const bf16x8*)&sV[(l31)      * VSTR + c * 16 + h * 8];
        bf16x8 v1 = *(const bf16x8*)&sV[(32 + l31) * VSTR + c * 16 + h * 8];
        o0 = __builtin_amdgcn_mfma_f32_32x32x16_bf16(v0, pfA[c], o0, 0, 0, 0);
        o1 = __builtin_amdgcn_mfma_f32_32x32x16_bf16(v1, pfA[c], o1, 0, 0, 0);
      }
    }

    // ---- sub-step B: softmax(s2,s3) + pack + PV (V cols 64..127) ----
    {
      float mx = -1e30f;
#pragma unroll
      for (int r = 0; r < 16; r++) { mx = fmaxf(mx, s2[r]); mx = fmaxf(mx, s3[r]); }
      mx = fmaxf(mx, __shfl_xor(mx, 32, 64));
      const float nm = fmaxf(mrow, mx);
      const float alpha = EXP2F(mrow - nm);
      mrow = nm;
      float rs = 0.f;
#pragma unroll
      for (int r = 0; r < 16; r++) {
        const float p0 = EXP2F(s2[r] - nm);
        const float p1 = EXP2F(s3[r] - nm);
        s2[r] = p0; s3[r] = p1;
        rs += p0 + p1;
      }
      rs += __shfl_xor(rs, 32, 64);
      lrow = lrow * alpha + rs;
#pragma unroll
      for (int r = 0; r < 16; r++) { o0[r] *= alpha; o1[r] *= alpha; }

      bf16x8 pfB[4];
#pragma unroll
      for (int g = 0; g < 2; g++) {
        const f32x16& sg = (g == 0) ? s2 : s3;
#pragma unroll
        for (int cp = 0; cp < 2; cp++) {
          bf16x4 pk0 = { (bf16)sg[8 * cp + 0], (bf16)sg[8 * cp + 1],
                         (bf16)sg[8 * cp + 2], (bf16)sg[8 * cp + 3] };
          bf16x4 pk1 = { (bf16)sg[8 * cp + 4], (bf16)sg[8 * cp + 5],
                         (bf16)sg[8 * cp + 6], (bf16)sg[8 * cp + 7] };
          uint2 w0 = *(uint2*)&pk0;
          uint2 w1 = *(uint2*)&pk1;
          unsigned send0 = h ? w0.x : w1.x;
          unsigned send1 = h ? w0.y : w1.y;
          unsigned recv0 = __shfl_xor(send0, 32, 64);
          unsigned recv1 = __shfl_xor(send1, 32, 64);
          union { unsigned u[4]; bf16x8 v; } f;
          f.u[0] = h ? recv0 : w0.x;
          f.u[1] = h ? recv1 : w0.y;
          f.u[2] = h ? w1.x : recv0;
          f.u[3] = h ? w1.y : recv1;
          pfB[2 * g + cp] = f.v;
        }
      }
#pragma unroll
      for (int c = 0; c < 4; c++) {
        bf16x8 v0 = *(const bf16x8*)&sV[(l31)      * VSTR + 64 + c * 16 + h * 8];
        bf16x8 v1 = *(const bf16x8*)&sV[(32 + l31) * VSTR + 64 + c * 16 + h * 8];
        o0 = __builtin_amdgcn_mfma_f32_32x32x16_bf16(v0, pfB[c], o0, 0, 0, 0);
        o1 = __builtin_amdgcn_mfma_f32_32x32x16_bf16(v1, pfB[c], o1, 0, 0, 0);
      }
    }

    __syncthreads();   // reads of buf[kt&1] done before next-iter staging
  }

  const int b = bh >> 4, head = bh & 15;
  const float inv = 1.f / lrow;
  const size_t base = ((size_t)b * SEQ + qrow) * DIMD + head * HDIM;
#pragma unroll
  for (int g = 0; g < 4; g++) {
    bf16x4 oa = { (bf16)(o0[4*g] * inv), (bf16)(o0[4*g+1] * inv),
                  (bf16)(o0[4*g+2] * inv), (bf16)(o0[4*g+3] * inv) };
    bf16x4 ob = { (bf16)(o1[4*g] * inv), (bf16)(o1[4*g+1] * inv),
                  (bf16)(o1[4*g+2] * inv), (bf16)(o1[4*g+3] * inv) };
    *(bf16x4*)&Ob[base + g * 8 + h * 4]      = oa;
    *(bf16x4*)&Ob[base + 32 + g * 8 + h * 4] = ob;
  }
}

extern "C" void kernel_launch(void* const* d_in, const int* in_sizes, int n_in,
                              void* d_out, int out_size, void* d_ws, size_t ws_size,
                              hipStream_t stream) {
  const float* x      = (const float*)d_in[0];
  const float* w_qkv  = (const float*)d_in[1];
  const float* b_qkv  = (const float*)d_in[2];
  const float* w_proj = (const float*)d_in[3];
  const float* b_proj = (const float*)d_in[4];
  float* out = (float*)d_out;
  char* ws = (char*)d_ws;

  bf16* Qb = (bf16*)d_out;
  bf16* Kb = (bf16*)d_out + (size_t)MTOT * DIMD;
  bf16* xb     = (bf16*)(ws + OFF_XB);
  bf16* Ob     = (bf16*)(ws + OFF_OB);   // overlays xb (dead after QKV GEMM)
  bf16* Vt     = (bf16*)(ws + OFF_VT);
  bf16* wprojb = (bf16*)(ws + OFF_WP);   // overlays Vt (dead after attn)

  cvt_kernel<<<(MTOT * DIMD / 4) / 256, 256, 0, stream>>>(x, xb, MTOT * DIMD / 4);
  gemm_qkv<<<dim3(24, 32), 256, 0, stream>>>(xb, w_qkv, b_qkv, Qb, Kb, Vt);
  attn_kernel<<<BATCH * NHEAD * (SEQ / 128), 256, 0, stream>>>(Qb, Kb, Vt, Ob);
  cvt_kernel<<<(DIMD * DIMD / 4) / 256, 256, 0, stream>>>(w_proj, wprojb, DIMD * DIMD / 4);
  gemm_proj<<<dim3(8, 64), 256, 0, stream>>>(Ob, wprojb, b_proj, out);
}

// Round 6
// 235.962 us; speedup vs baseline: 1.0157x; 1.0157x over previous
//
#include <hip/hip_runtime.h>

typedef __bf16 bf16;
typedef __bf16 bf16x4 __attribute__((ext_vector_type(4)));
typedef __bf16 bf16x8 __attribute__((ext_vector_type(8)));
typedef float f32x4 __attribute__((ext_vector_type(4)));
typedef float f32x16 __attribute__((ext_vector_type(16)));

#define DIMD 1024
#define NHEAD 16
#define HDIM 64
#define BATCH 2
#define SEQ 2048
#define MTOT (BATCH*SEQ)   // 4096

#define EXP2F(x) __builtin_amdgcn_exp2f(x)

// ---- memory plan (total ws use = 16 MB) ----
// d_out: [0,8MB) Qb bf16 (pre-scaled 0.125*log2e); [8,16MB) Kb   (dead after attn -> out)
// d_ws:  [0,8MB) xb bf16 -> dead after QKV GEMM, then Ob
//        [8,16MB) Vt bf16 -> dead after attn, then wprojb bf16 (2MB)
#define OFF_XB (0ull)
#define OFF_OB (0ull)
#define OFF_VT (8ull<<20)
#define OFF_WP (8ull<<20)

__device__ __forceinline__ void g2l16(const void* g, void* l) {
  __builtin_amdgcn_global_load_lds(
      (const __attribute__((address_space(1))) void*)g,
      (__attribute__((address_space(3))) void*)l,
      16, 0, 0);
}

__device__ __forceinline__ bf16x8 cvt8(float4 a, float4 b) {
  bf16x8 r = { (bf16)a.x, (bf16)a.y, (bf16)a.z, (bf16)a.w,
               (bf16)b.x, (bf16)b.y, (bf16)b.z, (bf16)b.w };
  return r;
}

// ---------------- fp32 -> bf16 conversion ----------------
__global__ __launch_bounds__(256) void cvt_kernel(const float* __restrict__ in,
                                                  bf16* __restrict__ out, int n4) {
  int i = blockIdx.x * blockDim.x + threadIdx.x;
  if (i < n4) {
    float4 v = ((const float4*)in)[i];
    bf16x4 o = { (bf16)v.x, (bf16)v.y, (bf16)v.z, (bf16)v.w };
    ((bf16x4*)out)[i] = o;
  }
}

// ---------------- QKV GEMM (R9/R10 inner loop; + XCD L2-blocking swizzle) ---
__global__ __launch_bounds__(256, 3) void gemm_qkv(
    const bf16* __restrict__ A, const float* __restrict__ W,
    const float* __restrict__ bias,
    bf16* __restrict__ Qb, bf16* __restrict__ Kb, bf16* __restrict__ Vt)
{
  __shared__ bf16 lA[2][128 * 32];
  __shared__ bf16 lB[2][128 * 32];
  const int tid = threadIdx.x;
  const int wave = tid >> 6, lane = tid & 63;
  const int l15 = lane & 15, quad = lane >> 4;
  const int wm = wave >> 1, wn = wave & 1;

  const int lin = blockIdx.y * 24 + blockIdx.x;   // 768 blocks, 768%8==0
  const int xcd = lin & 7, idx = lin >> 3;        // 96 blocks per XCD
  const int tn_i = xcd * 3 + idx % 3;             // 3 N-tiles per XCD stripe
  const int tm_i = idx / 3;                       // 32 M-tiles
  const int tm = tm_i * 128, tn = tn_i * 128;

  f32x4 acc[4][4] = {};

  const int srow = tid >> 2, sch = (tid & 3) * 8;
  const bf16*  ga = &A[(size_t)(tm + srow) * DIMD + sch];
  const float* gb = &W[(size_t)(tn + srow) * DIMD + sch];

  g2l16(ga,                     &lA[0][wave * 512]);
  g2l16(ga + (size_t)64 * DIMD, &lA[0][2048 + wave * 512]);
  float4 bv0 = ((const float4*)gb)[0], bv1 = ((const float4*)gb)[1];
  float4 bv2 = ((const float4*)(gb + (size_t)64 * DIMD))[0],
         bv3 = ((const float4*)(gb + (size_t)64 * DIMD))[1];

  for (int kt = 0; kt < 32; kt++) {
    bf16* sB = lB[kt & 1];
    *(bf16x8*)&sB[srow * 32 + sch]        = cvt8(bv0, bv1);
    *(bf16x8*)&sB[(64 + srow) * 32 + sch] = cvt8(bv2, bv3);
    __syncthreads();

    if (kt < 31) {
      const int kn = (kt + 1) * 32;
      bf16* nA = lA[(kt + 1) & 1];
      g2l16(ga + kn,                     &nA[wave * 512]);
      g2l16(ga + kn + (size_t)64 * DIMD, &nA[2048 + wave * 512]);
      const float* gbn = gb + kn;
      bv0 = ((const float4*)gbn)[0]; bv1 = ((const float4*)gbn)[1];
      bv2 = ((const float4*)(gbn + (size_t)64 * DIMD))[0];
      bv3 = ((const float4*)(gbn + (size_t)64 * DIMD))[1];
    }

    const bf16* sA = lA[kt & 1];
    bf16x8 af[4], bfr[4];
#pragma unroll
    for (int i = 0; i < 4; i++)
      af[i] = *(const bf16x8*)&sA[(wm * 64 + i * 16 + l15) * 32 + quad * 8];
#pragma unroll
    for (int i = 0; i < 4; i++)
      bfr[i] = *(const bf16x8*)&sB[(wn * 64 + i * 16 + l15) * 32 + quad * 8];
#pragma unroll
    for (int i = 0; i < 4; i++)
#pragma unroll
      for (int j = 0; j < 4; j++)
        acc[i][j] = __builtin_amdgcn_mfma_f32_16x16x32_bf16(af[i], bfr[j], acc[i][j], 0, 0, 0);
  }

  const int sel = tn >> 10;  // 0=Q 1=K 2=V
#pragma unroll
  for (int j = 0; j < 4; j++) {
    const int n = tn + wn * 64 + j * 16 + l15;
    const float bv = bias[n];
    const int d = n & 1023, h = d >> 6, hd = d & 63;
#pragma unroll
    for (int i = 0; i < 4; i++) {
      const int mbase = tm + wm * 64 + i * 16 + quad * 4;
      const int b = mbase >> 11, s0 = mbase & 2047;
      const int bh = b * NHEAD + h;
      if (sel == 2) {
        bf16x4 vv = { (bf16)(acc[i][j][0] + bv), (bf16)(acc[i][j][1] + bv),
                      (bf16)(acc[i][j][2] + bv), (bf16)(acc[i][j][3] + bv) };
        *(bf16x4*)&Vt[((size_t)bh * HDIM + hd) * SEQ + s0] = vv;
      } else {
#pragma unroll
        for (int r = 0; r < 4; r++) {
          float v = acc[i][j][r] + bv;
          if (sel == 0)
            Qb[((size_t)bh * SEQ + s0 + r) * HDIM + hd] = (bf16)(v * 0.18033688f); // 0.125*log2e
          else
            Kb[((size_t)bh * SEQ + s0 + r) * HDIM + hd] = (bf16)v;
        }
      }
    }
  }
}

// ---------------- proj GEMM v2: both operands async via global_load_lds ----
__global__ __launch_bounds__(256, 2) void gemm_proj(
    const bf16* __restrict__ A, const bf16* __restrict__ Bt,
    const float* __restrict__ bias, float* __restrict__ out)
{
  __shared__ bf16 lA[2][64 * 32];
  __shared__ bf16 lB[2][128 * 32];
  const int tid = threadIdx.x;
  const int wave = tid >> 6, lane = tid & 63;
  const int l15 = lane & 15, quad = lane >> 4;
  const int tm = blockIdx.y * 64, tn = blockIdx.x * 128;

  f32x4 acc[4][2] = {};

  const int srow = tid >> 2, sch = (tid & 3) * 8;
  const bf16* ga = &A[(size_t)(tm + srow) * DIMD + sch];
  const bf16* gb = &Bt[(size_t)(tn + srow) * DIMD + sch];

  g2l16(ga,                     &lA[0][wave * 512]);
  g2l16(gb,                     &lB[0][wave * 512]);
  g2l16(gb + (size_t)64 * DIMD, &lB[0][2048 + wave * 512]);

  for (int kt = 0; kt < 32; kt++) {
    __syncthreads();

    if (kt < 31) {
      const int kn = (kt + 1) * 32;
      bf16* nA = lA[(kt + 1) & 1];
      bf16* nB = lB[(kt + 1) & 1];
      g2l16(ga + kn,                     &nA[wave * 512]);
      g2l16(gb + kn,                     &nB[wave * 512]);
      g2l16(gb + kn + (size_t)64 * DIMD, &nB[2048 + wave * 512]);
    }

    const bf16* sA = lA[kt & 1];
    const bf16* sB = lB[kt & 1];
    bf16x8 af[4], bfr[2];
#pragma unroll
    for (int i = 0; i < 4; i++)
      af[i] = *(const bf16x8*)&sA[(i * 16 + l15) * 32 + quad * 8];
#pragma unroll
    for (int j = 0; j < 2; j++)
      bfr[j] = *(const bf16x8*)&sB[(wave * 32 + j * 16 + l15) * 32 + quad * 8];
#pragma unroll
    for (int i = 0; i < 4; i++)
#pragma unroll
      for (int j = 0; j < 2; j++)
        acc[i][j] = __builtin_amdgcn_mfma_f32_16x16x32_bf16(af[i], bfr[j], acc[i][j], 0, 0, 0);
  }

#pragma unroll
  for (int j = 0; j < 2; j++) {
    const int n = tn + wave * 32 + j * 16 + l15;
    const float bv = bias[n];
#pragma unroll
    for (int i = 0; i < 4; i++) {
      const int mbase = tm + i * 16 + quad * 4;
#pragma unroll
      for (int r = 0; r < 4; r++)
        out[(size_t)(mbase + r) * DIMD + n] = acc[i][j][r] + bv;
    }
  }
}

// ---------------- flash attention v12: v11 schedule + pinned occupancy ------
// v11 post-mortem: schedule correct (passed, absmax identical) but spilled —
// VGPR_Count=128 with 256 available (LDS 71.7KB caps CU at 2 blocks = 2
// waves/SIMD). Theory: backend occupancy heuristic targets 4 waves/EU
// (128-reg budget) and spills to reach it; launch_bounds only sets a MIN.
// Fix: amdgpu_waves_per_eu(2,2) pins the range -> 256-reg budget, no
// occupancy incentive to spill. Everything else byte-identical to v11.
// Tripwire: WRITE_SIZE must return to ~8192 KB; if not, KVBLK=128 is dead.
#define KSTR 72
#define VSTR 136
__global__ void __attribute__((amdgpu_waves_per_eu(2, 2)))
__launch_bounds__(256) attn_kernel(
    const bf16* __restrict__ Qb, const bf16* __restrict__ Kb,
    const bf16* __restrict__ Vt, bf16* __restrict__ Ob)
{
  __shared__ bf16 lK[2][128 * KSTR];   // 2 x 18432 B
  __shared__ bf16 lV[2][64 * VSTR];    // 2 x 17408 B   (total 71680 B)

  const int tid = threadIdx.x;
  const int wave = tid >> 6, lane = tid & 63;
  const int l31 = lane & 31, h = lane >> 5;
  const int xcd = blockIdx.x & 7, grp = blockIdx.x >> 3;
  const int bh = xcd + 8 * (grp & 3);
  const int qt = grp >> 2;

  const int qrow = qt * 128 + wave * 32 + l31;
  const bf16* qp = Qb + ((size_t)bh * SEQ + qrow) * HDIM + h * 8;
  bf16x8 qf[4];
#pragma unroll
  for (int c = 0; c < 4; c++) qf[c] = *(const bf16x8*)(qp + c * 16);

  const int srow = tid >> 3;            // 0..31
  const int sch = (tid & 7) * 8;        // bf16 elem offset in 64
  const bf16* kg = Kb + ((size_t)bh * SEQ + srow) * HDIM + sch;
  const bf16* vg = Vt + ((size_t)bh * HDIM + srow) * SEQ + sch;

  uint4 kr[4], vr[4];
#pragma unroll
  for (int i = 0; i < 4; i++)
    kr[i] = *(const uint4*)(kg + (size_t)(32 * i) * HDIM);
#pragma unroll
  for (int i = 0; i < 2; i++)
#pragma unroll
    for (int j = 0; j < 2; j++)
      vr[2 * i + j] = *(const uint4*)(vg + (size_t)(32 * i) * SEQ + j * 64);

  f32x16 o0 = {}, o1 = {};
  float mrow = -1e30f, lrow = 0.f;

  for (int kt = 0; kt < SEQ / 128; kt++) {
    bf16* sK = lK[kt & 1];
    bf16* sV = lV[kt & 1];
#pragma unroll
    for (int i = 0; i < 4; i++)
      *(uint4*)&sK[(srow + 32 * i) * KSTR + sch] = kr[i];
#pragma unroll
    for (int i = 0; i < 2; i++)
#pragma unroll
      for (int j = 0; j < 2; j++)
        *(uint4*)&sV[(srow + 32 * i) * VSTR + j * 64 + sch] = vr[2 * i + j];
    __syncthreads();

    if (kt < SEQ / 128 - 1) {
      const size_t koff = (size_t)(kt + 1) * 128;
#pragma unroll
      for (int i = 0; i < 4; i++)
        kr[i] = *(const uint4*)(kg + (koff + 32 * i) * HDIM);
#pragma unroll
      for (int i = 0; i < 2; i++)
#pragma unroll
        for (int j = 0; j < 2; j++)
          vr[2 * i + j] = *(const uint4*)(vg + (size_t)(32 * i) * SEQ + koff + j * 64);
    }

    // ---- QK for both sub-steps (B's MFMAs overlap A's softmax below) ----
    f32x16 s0 = {}, s1 = {}, s2 = {}, s3 = {};
#pragma unroll
    for (int c = 0; c < 4; c++) {
      bf16x8 k0 = *(const bf16x8*)&sK[(l31)      * KSTR + c * 16 + h * 8];
      bf16x8 k1 = *(const bf16x8*)&sK[(32 + l31) * KSTR + c * 16 + h * 8];
      s0 = __builtin_amdgcn_mfma_f32_32x32x16_bf16(k0, qf[c], s0, 0, 0, 0);
      s1 = __builtin_amdgcn_mfma_f32_32x32x16_bf16(k1, qf[c], s1, 0, 0, 0);
    }
#pragma unroll
    for (int c = 0; c < 4; c++) {
      bf16x8 k2 = *(const bf16x8*)&sK[(64 + l31) * KSTR + c * 16 + h * 8];
      bf16x8 k3 = *(const bf16x8*)&sK[(96 + l31) * KSTR + c * 16 + h * 8];
      s2 = __builtin_amdgcn_mfma_f32_32x32x16_bf16(k2, qf[c], s2, 0, 0, 0);
      s3 = __builtin_amdgcn_mfma_f32_32x32x16_bf16(k3, qf[c], s3, 0, 0, 0);
    }

    // ---- sub-step A: softmax(s0,s1) + pack + PV (V cols 0..63) ----
    {
      float mx = -1e30f;
#pragma unroll
      for (int r = 0; r < 16; r++) { mx = fmaxf(mx, s0[r]); mx = fmaxf(mx, s1[r]); }
      mx = fmaxf(mx, __shfl_xor(mx, 32, 64));
      const float nm = fmaxf(mrow, mx);
      const float alpha = EXP2F(mrow - nm);
      mrow = nm;
      float rs = 0.f;
#pragma unroll
      for (int r = 0; r < 16; r++) {
        const float p0 = EXP2F(s0[r] - nm);
        const float p1 = EXP2F(s1[r] - nm);
        s0[r] = p0; s1[r] = p1;
        rs += p0 + p1;
      }
      rs += __shfl_xor(rs, 32, 64);
      lrow = lrow * alpha + rs;
#pragma unroll
      for (int r = 0; r < 16; r++) { o0[r] *= alpha; o1[r] *= alpha; }

      bf16x8 pfA[4];
#pragma unroll
      for (int g = 0; g < 2; g++) {
        const f32x16& sg = (g == 0) ? s0 : s1;
#pragma unroll
        for (int cp = 0; cp < 2; cp++) {
          bf16x4 pk0 = { (bf16)sg[8 * cp + 0], (bf16)sg[8 * cp + 1],
                         (bf16)sg[8 * cp + 2], (bf16)sg[8 * cp + 3] };
          bf16x4 pk1 = { (bf16)sg[8 * cp + 4], (bf16)sg[8 * cp + 5],
                         (bf16)sg[8 * cp + 6], (bf16)sg[8 * cp + 7] };
          uint2 w0 = *(uint2*)&pk0;
          uint2 w1 = *(uint2*)&pk1;
          unsigned send0 = h ? w0.x : w1.x;
          unsigned send1 = h ? w0.y : w1.y;
          unsigned recv0 = __shfl_xor(send0, 32, 64);
          unsigned recv1 = __shfl_xor(send1, 32, 64);
          union { unsigned u[4]; bf16x8 v; } f;
          f.u[0] = h ? recv0 : w0.x;
          f.u[1] = h ? recv1 : w0.y;
          f.u[2] = h ? w1.x : recv0;
          f.u[3] = h ? w1.y : recv1;
          pfA[2 * g + cp] = f.v;
        }
      }
#pragma unroll
      for (int c = 0; c < 4; c++) {
        bf16x8 v0 = *(const bf16x8*)&sV[(l31)      * VSTR + c * 16 + h * 8];
        bf16x8 v1 = *(const bf16x8*)&sV[(32 + l31) * VSTR + c * 16 + h * 8];
        o0 = __builtin_amdgcn_mfma_f32_32x32x16_bf16(v0, pfA[c], o0, 0, 0, 0);
        o1 = __builtin_amdgcn_mfma_f32_32x32x16_bf16(v1, pfA[c], o1, 0, 0, 0);
      }
    }

    // ---- sub-step B: softmax(s2,s3) + pack + PV (V cols 64..127) ----
    {
      float mx = -1e30f;
#pragma unroll
      for (int r = 0; r < 16; r++) { mx = fmaxf(mx, s2[r]); mx = fmaxf(mx, s3[r]); }
      mx = fmaxf(mx, __shfl_xor(mx, 32, 64));
      const float nm = fmaxf(mrow, mx);
      const float alpha = EXP2F(mrow - nm);
      mrow = nm;
      float rs = 0.f;
#pragma unroll
      for (int r = 0; r < 16; r++) {
        const float p0 = EXP2F(s2[r] - nm);
        const float p1 = EXP2F(s3[r] - nm);
        s2[r] = p0; s3[r] = p1;
        rs += p0 + p1;
      }
      rs += __shfl_xor(rs, 32, 64);
      lrow = lrow * alpha + rs;
#pragma unroll
      for (int r = 0; r < 16; r++) { o0[r] *= alpha; o1[r] *= alpha; }

      bf16x8 pfB[4];
#pragma unroll
      for (int g = 0; g < 2; g++) {
        const f32x16& sg = (g == 0) ? s2 : s3;
#pragma unroll
        for (int cp = 0; cp < 2; cp++) {
          bf16x4 pk0 = { (bf16)sg[8 * cp + 0], (bf16)sg[8 * cp + 1],
                         (bf16)sg[8 * cp + 2], (bf16)sg[8 * cp + 3] };
          bf16x4 pk1 = { (bf16)sg[8 * cp + 4], (bf16)sg[8 * cp + 5],
                         (bf16)sg[8 * cp + 6], (bf16)sg[8 * cp + 7] };
          uint2 w0 = *(uint2*)&pk0;
          uint2 w1 = *(uint2*)&pk1;
          unsigned send0 = h ? w0.x : w1.x;
          unsigned send1 = h ? w0.y : w1.y;
          unsigned recv0 = __shfl_xor(send0, 32, 64);
          unsigned recv1 = __shfl_xor(send1, 32, 64);
          union { unsigned u[4]; bf16x8 v; } f;
          f.u[0] = h ? recv0 : w0.x;
          f.u[1] = h ? recv1 : w0.y;
          f.u[2] = h ? w1.x : recv0;
          f.u[3] = h ? w1.y : recv1;
          pfB[2 * g + cp] = f.v;
        }
      }
#pragma unroll
      for (int c = 0; c < 4; c++) {
        bf16x8 v0 = *(const bf16x8*)&sV[(l31)      * VSTR + 64 + c * 16 + h * 8];
        bf16x8 v1 = *(const bf16x8*)&sV[(32 + l31) * VSTR + 64 + c * 16 + h * 8];
        o0 = __builtin_amdgcn_mfma_f32_32x32x16_bf16(v0, pfB[c], o0, 0, 0, 0);
        o1 = __builtin_amdgcn_mfma_f32_32x32x16_bf16(v1, pfB[c], o1, 0, 0, 0);
      }
    }

    __syncthreads();   // reads of buf[kt&1] done before next-iter staging
  }

  const int b = bh >> 4, head = bh & 15;
  const float inv = 1.f / lrow;
  const size_t base = ((size_t)b * SEQ + qrow) * DIMD + head * HDIM;
#pragma unroll
  for (int g = 0; g < 4; g++) {
    bf16x4 oa = { (bf16)(o0[4*g] * inv), (bf16)(o0[4*g+1] * inv),
                  (bf16)(o0[4*g+2] * inv), (bf16)(o0[4*g+3] * inv) };
    bf16x4 ob = { (bf16)(o1[4*g] * inv), (bf16)(o1[4*g+1] * inv),
                  (bf16)(o1[4*g+2] * inv), (bf16)(o1[4*g+3] * inv) };
    *(bf16x4*)&Ob[base + g * 8 + h * 4]      = oa;
    *(bf16x4*)&Ob[base + 32 + g * 8 + h * 4] = ob;
  }
}

extern "C" void kernel_launch(void* const* d_in, const int* in_sizes, int n_in,
                              void* d_out, int out_size, void* d_ws, size_t ws_size,
                              hipStream_t stream) {
  const float* x      = (const float*)d_in[0];
  const float* w_qkv  = (const float*)d_in[1];
  const float* b_qkv  = (const float*)d_in[2];
  const float* w_proj = (const float*)d_in[3];
  const float* b_proj = (const float*)d_in[4];
  float* out = (float*)d_out;
  char* ws = (char*)d_ws;

  bf16* Qb = (bf16*)d_out;
  bf16* Kb = (bf16*)d_out + (size_t)MTOT * DIMD;
  bf16* xb     = (bf16*)(ws + OFF_XB);
  bf16* Ob     = (bf16*)(ws + OFF_OB);   // overlays xb (dead after QKV GEMM)
  bf16* Vt     = (bf16*)(ws + OFF_VT);
  bf16* wprojb = (bf16*)(ws + OFF_WP);   // overlays Vt (dead after attn)

  cvt_kernel<<<(MTOT * DIMD / 4) / 256, 256, 0, stream>>>(x, xb, MTOT * DIMD / 4);
  gemm_qkv<<<dim3(24, 32), 256, 0, stream>>>(xb, w_qkv, b_qkv, Qb, Kb, Vt);
  attn_kernel<<<BATCH * NHEAD * (SEQ / 128), 256, 0, stream>>>(Qb, Kb, Vt, Ob);
  cvt_kernel<<<(DIMD * DIMD / 4) / 256, 256, 0, stream>>>(w_proj, wprojb, DIMD * DIMD / 4);
  gemm_proj<<<dim3(8, 64), 256, 0, stream>>>(Ob, wprojb, b_proj, out);
}

// Round 7
// 201.918 us; speedup vs baseline: 1.1870x; 1.1686x over previous
//
#include <hip/hip_runtime.h>

typedef __bf16 bf16;
typedef __bf16 bf16x4 __attribute__((ext_vector_type(4)));
typedef __bf16 bf16x8 __attribute__((ext_vector_type(8)));
typedef float f32x4 __attribute__((ext_vector_type(4)));
typedef float f32x16 __attribute__((ext_vector_type(16)));

#define DIMD 1024
#define NHEAD 16
#define HDIM 64
#define BATCH 2
#define SEQ 2048
#define MTOT (BATCH*SEQ)   // 4096

#define EXP2F(x) __builtin_amdgcn_exp2f(x)

// ---- memory plan ----
// d_out: [0,8MB) Qb bf16 (pre-scaled 0.125*log2e); [8,16MB) Kb   (dead after attn -> out)
// d_ws:  [0,8MB) xb bf16 -> dead after QKV GEMM, then Ob
//        [8,16MB) Vt bf16  (w_proj now consumed in f32 directly by gemm_proj)
#define OFF_XB (0ull)
#define OFF_OB (0ull)
#define OFF_VT (8ull<<20)

__device__ __forceinline__ void g2l16(const void* g, void* l) {
  __builtin_amdgcn_global_load_lds(
      (const __attribute__((address_space(1))) void*)g,
      (__attribute__((address_space(3))) void*)l,
      16, 0, 0);
}

__device__ __forceinline__ bf16x8 cvt8(float4 a, float4 b) {
  bf16x8 r = { (bf16)a.x, (bf16)a.y, (bf16)a.z, (bf16)a.w,
               (bf16)b.x, (bf16)b.y, (bf16)b.z, (bf16)b.w };
  return r;
}

// ---------------- fp32 -> bf16 conversion (x only; w_proj cvt now fused) ----
__global__ __launch_bounds__(256) void cvt_kernel(const float* __restrict__ in,
                                                  bf16* __restrict__ out, int n4) {
  int i = blockIdx.x * blockDim.x + threadIdx.x;
  if (i < n4) {
    float4 v = ((const float4*)in)[i];
    bf16x4 o = { (bf16)v.x, (bf16)v.y, (bf16)v.z, (bf16)v.w };
    ((bf16x4*)out)[i] = o;
  }
}

// ---------------- QKV GEMM (unchanged — R9/R10 proven, round-4 state) -------
__global__ __launch_bounds__(256, 3) void gemm_qkv(
    const bf16* __restrict__ A, const float* __restrict__ W,
    const float* __restrict__ bias,
    bf16* __restrict__ Qb, bf16* __restrict__ Kb, bf16* __restrict__ Vt)
{
  __shared__ bf16 lA[2][128 * 32];
  __shared__ bf16 lB[2][128 * 32];
  const int tid = threadIdx.x;
  const int wave = tid >> 6, lane = tid & 63;
  const int l15 = lane & 15, quad = lane >> 4;
  const int wm = wave >> 1, wn = wave & 1;
  const int tm = blockIdx.y * 128, tn = blockIdx.x * 128;

  f32x4 acc[4][4] = {};

  const int srow = tid >> 2, sch = (tid & 3) * 8;
  const bf16*  ga = &A[(size_t)(tm + srow) * DIMD + sch];
  const float* gb = &W[(size_t)(tn + srow) * DIMD + sch];

  g2l16(ga,                     &lA[0][wave * 512]);
  g2l16(ga + (size_t)64 * DIMD, &lA[0][2048 + wave * 512]);
  float4 bv0 = ((const float4*)gb)[0], bv1 = ((const float4*)gb)[1];
  float4 bv2 = ((const float4*)(gb + (size_t)64 * DIMD))[0],
         bv3 = ((const float4*)(gb + (size_t)64 * DIMD))[1];

  for (int kt = 0; kt < 32; kt++) {
    bf16* sB = lB[kt & 1];
    *(bf16x8*)&sB[srow * 32 + sch]        = cvt8(bv0, bv1);
    *(bf16x8*)&sB[(64 + srow) * 32 + sch] = cvt8(bv2, bv3);
    __syncthreads();

    if (kt < 31) {
      const int kn = (kt + 1) * 32;
      bf16* nA = lA[(kt + 1) & 1];
      g2l16(ga + kn,                     &nA[wave * 512]);
      g2l16(ga + kn + (size_t)64 * DIMD, &nA[2048 + wave * 512]);
      const float* gbn = gb + kn;
      bv0 = ((const float4*)gbn)[0]; bv1 = ((const float4*)gbn)[1];
      bv2 = ((const float4*)(gbn + (size_t)64 * DIMD))[0];
      bv3 = ((const float4*)(gbn + (size_t)64 * DIMD))[1];
    }

    const bf16* sA = lA[kt & 1];
    bf16x8 af[4], bfr[4];
#pragma unroll
    for (int i = 0; i < 4; i++)
      af[i] = *(const bf16x8*)&sA[(wm * 64 + i * 16 + l15) * 32 + quad * 8];
#pragma unroll
    for (int i = 0; i < 4; i++)
      bfr[i] = *(const bf16x8*)&sB[(wn * 64 + i * 16 + l15) * 32 + quad * 8];
#pragma unroll
    for (int i = 0; i < 4; i++)
#pragma unroll
      for (int j = 0; j < 4; j++)
        acc[i][j] = __builtin_amdgcn_mfma_f32_16x16x32_bf16(af[i], bfr[j], acc[i][j], 0, 0, 0);
  }

  const int sel = tn >> 10;  // 0=Q 1=K 2=V
#pragma unroll
  for (int j = 0; j < 4; j++) {
    const int n = tn + wn * 64 + j * 16 + l15;
    const float bv = bias[n];
    const int d = n & 1023, h = d >> 6, hd = d & 63;
#pragma unroll
    for (int i = 0; i < 4; i++) {
      const int mbase = tm + wm * 64 + i * 16 + quad * 4;
      const int b = mbase >> 11, s0 = mbase & 2047;
      const int bh = b * NHEAD + h;
      if (sel == 2) {
        bf16x4 vv = { (bf16)(acc[i][j][0] + bv), (bf16)(acc[i][j][1] + bv),
                      (bf16)(acc[i][j][2] + bv), (bf16)(acc[i][j][3] + bv) };
        *(bf16x4*)&Vt[((size_t)bh * HDIM + hd) * SEQ + s0] = vv;
      } else {
#pragma unroll
        for (int r = 0; r < 4; r++) {
          float v = acc[i][j][r] + bv;
          if (sel == 0)
            Qb[((size_t)bh * SEQ + s0 + r) * HDIM + hd] = (bf16)(v * 0.18033688f); // 0.125*log2e
          else
            Kb[((size_t)bh * SEQ + s0 + r) * HDIM + hd] = (bf16)v;
        }
      }
    }
  }
}

// ---------------- proj GEMM v3: consumes w_proj f32 directly ----------------
// B-path = gemm_qkv's proven f32 reg-stage + cvt8 pattern (write sB -> barrier
// -> prefetch regs); A stays async g2l16. Deletes the second cvt_kernel and
// its graph slot, and removes the wprojb/Vt aliasing constraint.
__global__ __launch_bounds__(256, 2) void gemm_proj(
    const bf16* __restrict__ A, const float* __restrict__ W,
    const float* __restrict__ bias, float* __restrict__ out)
{
  __shared__ bf16 lA[2][64 * 32];
  __shared__ bf16 lB[2][128 * 32];
  const int tid = threadIdx.x;
  const int wave = tid >> 6, lane = tid & 63;
  const int l15 = lane & 15, quad = lane >> 4;
  const int tm = blockIdx.y * 64, tn = blockIdx.x * 128;

  f32x4 acc[4][2] = {};

  const int srow = tid >> 2, sch = (tid & 3) * 8;
  const bf16*  ga = &A[(size_t)(tm + srow) * DIMD + sch];
  const float* gb = &W[(size_t)(tn + srow) * DIMD + sch];

  g2l16(ga, &lA[0][wave * 512]);
  float4 bv0 = ((const float4*)gb)[0], bv1 = ((const float4*)gb)[1];
  float4 bv2 = ((const float4*)(gb + (size_t)64 * DIMD))[0],
         bv3 = ((const float4*)(gb + (size_t)64 * DIMD))[1];

  for (int kt = 0; kt < 32; kt++) {
    bf16* sB = lB[kt & 1];
    *(bf16x8*)&sB[srow * 32 + sch]        = cvt8(bv0, bv1);
    *(bf16x8*)&sB[(64 + srow) * 32 + sch] = cvt8(bv2, bv3);
    __syncthreads();   // drains g2l16 A(kt); orders sB writes vs reads

    if (kt < 31) {
      const int kn = (kt + 1) * 32;
      g2l16(ga + kn, &lA[(kt + 1) & 1][wave * 512]);
      const float* gbn = gb + kn;
      bv0 = ((const float4*)gbn)[0]; bv1 = ((const float4*)gbn)[1];
      bv2 = ((const float4*)(gbn + (size_t)64 * DIMD))[0];
      bv3 = ((const float4*)(gbn + (size_t)64 * DIMD))[1];
    }

    const bf16* sA = lA[kt & 1];
    bf16x8 af[4], bfr[2];
#pragma unroll
    for (int i = 0; i < 4; i++)
      af[i] = *(const bf16x8*)&sA[(i * 16 + l15) * 32 + quad * 8];
#pragma unroll
    for (int j = 0; j < 2; j++)
      bfr[j] = *(const bf16x8*)&sB[(wave * 32 + j * 16 + l15) * 32 + quad * 8];
#pragma unroll
    for (int i = 0; i < 4; i++)
#pragma unroll
      for (int j = 0; j < 2; j++)
        acc[i][j] = __builtin_amdgcn_mfma_f32_16x16x32_bf16(af[i], bfr[j], acc[i][j], 0, 0, 0);
  }

#pragma unroll
  for (int j = 0; j < 2; j++) {
    const int n = tn + wave * 32 + j * 16 + l15;
    const float bv = bias[n];
#pragma unroll
    for (int i = 0; i < 4; i++) {
      const int mbase = tm + i * 16 + quad * 4;
#pragma unroll
      for (int r = 0; r < 4; r++)
        out[(size_t)(mbase + r) * DIMD + n] = acc[i][j][r] + bv;
    }
  }
}

// ---------------- flash attention v10 (exact revert — measured 57.6us) ------
// KVBLK=128 variants (v9/v11/v12) all spill: with 6 live f32x16 the unified
// VGPR/AGPR file caps arch-VGPRs at 128 regardless of waves_per_eu — the
// structure is dead. v10 = v6 memory structure + in-register P (pack +
// __shfl_xor half-exchange), 0 bank conflicts, VGPR 64.
#define LSTR 72
__global__ __launch_bounds__(256, 2) void attn_kernel(
    const bf16* __restrict__ Qb, const bf16* __restrict__ Kb,
    const bf16* __restrict__ Vt, bf16* __restrict__ Ob)
{
  __shared__ bf16 lKV[2][2][64 * LSTR];   // [buf][K=0/V=1]

  const int tid = threadIdx.x;
  const int wave = tid >> 6, lane = tid & 63;
  const int l31 = lane & 31, h = lane >> 5;
  const int xcd = blockIdx.x & 7, grp = blockIdx.x >> 3;
  const int bh = xcd + 8 * (grp & 3);
  const int qt = grp >> 2;

  const int qrow = qt * 128 + wave * 32 + l31;
  const bf16* qp = Qb + ((size_t)bh * SEQ + qrow) * HDIM + h * 8;
  bf16x8 qf[4];
#pragma unroll
  for (int c = 0; c < 4; c++) qf[c] = *(const bf16x8*)(qp + c * 16);

  const int srow = tid >> 3;            // 0..31
  const int sch = (tid & 7) * 8;        // bf16 elem offset in 64
  const bf16* kg = Kb + ((size_t)bh * SEQ + srow) * HDIM + sch;
  const bf16* vg = Vt + ((size_t)bh * HDIM + srow) * SEQ + sch;

  uint4 kr0 = *(const uint4*)(kg);
  uint4 kr1 = *(const uint4*)(kg + 32 * HDIM);
  uint4 vr0 = *(const uint4*)(vg);
  uint4 vr1 = *(const uint4*)(vg + 32 * SEQ);

  bf16x8 pf[4];   // packed P(t-1), replaces lP

  f32x16 o0 = {}, o1 = {};
  float mrow = -1e30f, lrow = 0.f;

  for (int kt = 0; kt < SEQ / 64; kt++) {
    bf16* sK = lKV[kt & 1][0];
    bf16* sV = lKV[kt & 1][1];
    *(uint4*)&sK[srow * LSTR + sch]        = kr0;
    *(uint4*)&sK[(32 + srow) * LSTR + sch] = kr1;
    *(uint4*)&sV[srow * LSTR + sch]        = vr0;
    *(uint4*)&sV[(32 + srow) * LSTR + sch] = vr1;
    __syncthreads();

    const int ktn = (kt + 1) & (SEQ / 64 - 1);
    kr0 = *(const uint4*)(kg + (size_t)ktn * 64 * HDIM);
    kr1 = *(const uint4*)(kg + (size_t)ktn * 64 * HDIM + 32 * HDIM);
    vr0 = *(const uint4*)(vg + ktn * 64);
    vr1 = *(const uint4*)(vg + ktn * 64 + 32 * SEQ);

    // S^T(t) = K Q^T : issue first so softmax's dependency is in flight
    f32x16 s0 = {}, s1 = {};
#pragma unroll
    for (int c = 0; c < 4; c++) {
      bf16x8 k0 = *(const bf16x8*)&sK[l31 * LSTR + c * 16 + h * 8];
      bf16x8 k1 = *(const bf16x8*)&sK[(32 + l31) * LSTR + c * 16 + h * 8];
      s0 = __builtin_amdgcn_mfma_f32_32x32x16_bf16(k0, qf[c], s0, 0, 0, 0);
      s1 = __builtin_amdgcn_mfma_f32_32x32x16_bf16(k1, qf[c], s1, 0, 0, 0);
    }

    // PV(t-1): P in pf regs, V(t-1) in the OTHER KV buffer.
    if (kt > 0) {
      const bf16* pV = lKV[(kt + 1) & 1][1];
#pragma unroll
      for (int c = 0; c < 4; c++) {
        bf16x8 v0 = *(const bf16x8*)&pV[l31 * LSTR + c * 16 + h * 8];
        bf16x8 v1 = *(const bf16x8*)&pV[(32 + l31) * LSTR + c * 16 + h * 8];
        o0 = __builtin_amdgcn_mfma_f32_32x32x16_bf16(v0, pf[c], o0, 0, 0, 0);
        o1 = __builtin_amdgcn_mfma_f32_32x32x16_bf16(v1, pf[c], o1, 0, 0, 0);
      }
    }

    // softmax(t)
    float mx = -1e30f;
#pragma unroll
    for (int r = 0; r < 16; r++) { mx = fmaxf(mx, s0[r]); mx = fmaxf(mx, s1[r]); }
    mx = fmaxf(mx, __shfl_xor(mx, 32, 64));
    const float nm = fmaxf(mrow, mx);
    const float alpha = EXP2F(mrow - nm);
    mrow = nm;

    float rs = 0.f;
#pragma unroll
    for (int r = 0; r < 16; r++) {
      const float p0 = EXP2F(s0[r] - nm);
      const float p1 = EXP2F(s1[r] - nm);
      s0[r] = p0; s1[r] = p1;
      rs += p0 + p1;
    }
    rs += __shfl_xor(rs, 32, 64);
    lrow = lrow * alpha + rs;

    // o-rescale: must follow PV(t-1) completion (reg dependency enforces)
#pragma unroll
    for (int r = 0; r < 16; r++) { o0[r] *= alpha; o1[r] *= alpha; }

    // pack P(t) -> pf regs via half-exchange
#pragma unroll
    for (int g = 0; g < 2; g++) {
      const f32x16& sg = (g == 0) ? s0 : s1;
#pragma unroll
      for (int cp = 0; cp < 2; cp++) {
        bf16x4 pk0 = { (bf16)sg[8 * cp + 0], (bf16)sg[8 * cp + 1],
                       (bf16)sg[8 * cp + 2], (bf16)sg[8 * cp + 3] };   // q=2cp
        bf16x4 pk1 = { (bf16)sg[8 * cp + 4], (bf16)sg[8 * cp + 5],
                       (bf16)sg[8 * cp + 6], (bf16)sg[8 * cp + 7] };   // q=2cp+1
        uint2 w0 = *(uint2*)&pk0;
        uint2 w1 = *(uint2*)&pk1;
        unsigned send0 = h ? w0.x : w1.x;
        unsigned send1 = h ? w0.y : w1.y;
        unsigned recv0 = __shfl_xor(send0, 32, 64);
        unsigned recv1 = __shfl_xor(send1, 32, 64);
        union { unsigned u[4]; bf16x8 v; } f;
        f.u[0] = h ? recv0 : w0.x;   // j0j1  (h'=0 source)
        f.u[1] = h ? recv1 : w0.y;   // j2j3
        f.u[2] = h ? w1.x : recv0;   // j4j5  (h'=1 source)
        f.u[3] = h ? w1.y : recv1;   // j6j7
        pf[2 * g + cp] = f.v;
      }
    }
  }

  // drain: PV(31) from buf[31&1 = 1], P in pf regs
  {
    const bf16* pV = lKV[1][1];
#pragma unroll
    for (int c = 0; c < 4; c++) {
      bf16x8 v0 = *(const bf16x8*)&pV[l31 * LSTR + c * 16 + h * 8];
      bf16x8 v1 = *(const bf16x8*)&pV[(32 + l31) * LSTR + c * 16 + h * 8];
      o0 = __builtin_amdgcn_mfma_f32_32x32x16_bf16(v0, pf[c], o0, 0, 0, 0);
      o1 = __builtin_amdgcn_mfma_f32_32x32x16_bf16(v1, pf[c], o1, 0, 0, 0);
    }
  }

  const int b = bh >> 4, head = bh & 15;
  const float inv = 1.f / lrow;
  const size_t base = ((size_t)b * SEQ + qrow) * DIMD + head * HDIM;
#pragma unroll
  for (int g = 0; g < 4; g++) {
    bf16x4 oa = { (bf16)(o0[4*g] * inv), (bf16)(o0[4*g+1] * inv),
                  (bf16)(o0[4*g+2] * inv), (bf16)(o0[4*g+3] * inv) };
    bf16x4 ob = { (bf16)(o1[4*g] * inv), (bf16)(o1[4*g+1] * inv),
                  (bf16)(o1[4*g+2] * inv), (bf16)(o1[4*g+3] * inv) };
    *(bf16x4*)&Ob[base + g * 8 + h * 4]      = oa;
    *(bf16x4*)&Ob[base + 32 + g * 8 + h * 4] = ob;
  }
}

extern "C" void kernel_launch(void* const* d_in, const int* in_sizes, int n_in,
                              void* d_out, int out_size, void* d_ws, size_t ws_size,
                              hipStream_t stream) {
  const float* x      = (const float*)d_in[0];
  const float* w_qkv  = (const float*)d_in[1];
  const float* b_qkv  = (const float*)d_in[2];
  const float* w_proj = (const float*)d_in[3];
  const float* b_proj = (const float*)d_in[4];
  float* out = (float*)d_out;
  char* ws = (char*)d_ws;

  bf16* Qb = (bf16*)d_out;
  bf16* Kb = (bf16*)d_out + (size_t)MTOT * DIMD;
  bf16* xb = (bf16*)(ws + OFF_XB);
  bf16* Ob = (bf16*)(ws + OFF_OB);   // overlays xb (dead after QKV GEMM)
  bf16* Vt = (bf16*)(ws + OFF_VT);

  cvt_kernel<<<(MTOT * DIMD / 4) / 256, 256, 0, stream>>>(x, xb, MTOT * DIMD / 4);
  gemm_qkv<<<dim3(24, 32), 256, 0, stream>>>(xb, w_qkv, b_qkv, Qb, Kb, Vt);
  attn_kernel<<<BATCH * NHEAD * (SEQ / 128), 256, 0, stream>>>(Qb, Kb, Vt, Ob);
  gemm_proj<<<dim3(8, 64), 256, 0, stream>>>(Ob, w_proj, b_proj, out);
}

// Round 8
// 190.099 us; speedup vs baseline: 1.2608x; 1.0622x over previous
//
#include <hip/hip_runtime.h>

typedef __bf16 bf16;
typedef __bf16 bf16x4 __attribute__((ext_vector_type(4)));
typedef __bf16 bf16x8 __attribute__((ext_vector_type(8)));
typedef float f32x4 __attribute__((ext_vector_type(4)));
typedef float f32x16 __attribute__((ext_vector_type(16)));

#define DIMD 1024
#define NHEAD 16
#define HDIM 64
#define BATCH 2
#define SEQ 2048
#define MTOT (BATCH*SEQ)   // 4096

#define EXP2F(x) __builtin_amdgcn_exp2f(x)

// ---- memory plan (ws_size ~= 256 MiB per fillBufferAligned WRITE_SIZE) ----
// d_out: [0,8MB) Qb bf16 (pre-scaled 0.125*log2e); [8,16MB) Kb
// d_ws:  [0,8MB)  xb bf16 -> dead after QKV GEMM, then Ob
//        [8,16MB) Vt bf16 -> dead after attn, then wprojb bf16 (2MB)
//        [16,22MB) wqkvb bf16 (NEW — enabled by 256MiB ws)
#define OFF_XB (0ull)
#define OFF_OB (0ull)
#define OFF_VT (8ull<<20)
#define OFF_WP (8ull<<20)
#define OFF_WQ (16ull<<20)

__device__ __forceinline__ void g2l16(const void* g, void* l) {
  __builtin_amdgcn_global_load_lds(
      (const __attribute__((address_space(1))) void*)g,
      (__attribute__((address_space(3))) void*)l,
      16, 0, 0);
}

// ---------------- fp32 -> bf16 conversion ----------------
__global__ __launch_bounds__(256) void cvt_kernel(const float* __restrict__ in,
                                                  bf16* __restrict__ out, int n4) {
  int i = blockIdx.x * blockDim.x + threadIdx.x;
  if (i < n4) {
    float4 v = ((const float4*)in)[i];
    bf16x4 o = { (bf16)v.x, (bf16)v.y, (bf16)v.z, (bf16)v.w };
    ((bf16x4*)out)[i] = o;
  }
}

// fused: x (1M float4) + w_qkv (768K float4) in one launch
__global__ __launch_bounds__(256) void cvt2_kernel(
    const float* __restrict__ x, const float* __restrict__ wq,
    bf16* __restrict__ xb, bf16* __restrict__ wqb) {
  const int NX = MTOT * DIMD / 4;
  const int NW = 3 * DIMD * DIMD / 4;
  int i = blockIdx.x * blockDim.x + threadIdx.x;
  if (i < NX) {
    float4 v = ((const float4*)x)[i];
    bf16x4 o = { (bf16)v.x, (bf16)v.y, (bf16)v.z, (bf16)v.w };
    ((bf16x4*)xb)[i] = o;
  } else if (i < NX + NW) {
    int j = i - NX;
    float4 v = ((const float4*)wq)[j];
    bf16x4 o = { (bf16)v.x, (bf16)v.y, (bf16)v.z, (bf16)v.w };
    ((bf16x4*)wqb)[j] = o;
  }
}

// ---------------- QKV GEMM v2: BOTH operands async via g2l16 ----------------
// Was: B f32 reg-stage + cvt8 + ds_write (VALU-heavy). Now W pre-converted
// (wqkvb) -> 4 g2l16/iter, zero-VALU staging, single barrier — the exact
// schedule proven in gemm_proj v2 / m97 ladder. Epilogue unchanged.
__global__ __launch_bounds__(256, 3) void gemm_qkv(
    const bf16* __restrict__ A, const bf16* __restrict__ Bt,
    const float* __restrict__ bias,
    bf16* __restrict__ Qb, bf16* __restrict__ Kb, bf16* __restrict__ Vt)
{
  __shared__ bf16 lA[2][128 * 32];
  __shared__ bf16 lB[2][128 * 32];
  const int tid = threadIdx.x;
  const int wave = tid >> 6, lane = tid & 63;
  const int l15 = lane & 15, quad = lane >> 4;
  const int wm = wave >> 1, wn = wave & 1;
  const int tm = blockIdx.y * 128, tn = blockIdx.x * 128;

  f32x4 acc[4][4] = {};

  const int srow = tid >> 2, sch = (tid & 3) * 8;
  const bf16* ga = &A[(size_t)(tm + srow) * DIMD + sch];
  const bf16* gb = &Bt[(size_t)(tn + srow) * DIMD + sch];

  g2l16(ga,                     &lA[0][wave * 512]);
  g2l16(ga + (size_t)64 * DIMD, &lA[0][2048 + wave * 512]);
  g2l16(gb,                     &lB[0][wave * 512]);
  g2l16(gb + (size_t)64 * DIMD, &lB[0][2048 + wave * 512]);

  for (int kt = 0; kt < 32; kt++) {
    __syncthreads();   // drains g2l16(kt); separates buf rewrite from t-1 reads

    if (kt < 31) {
      const int kn = (kt + 1) * 32;
      bf16* nA = lA[(kt + 1) & 1];
      bf16* nB = lB[(kt + 1) & 1];
      g2l16(ga + kn,                     &nA[wave * 512]);
      g2l16(ga + kn + (size_t)64 * DIMD, &nA[2048 + wave * 512]);
      g2l16(gb + kn,                     &nB[wave * 512]);
      g2l16(gb + kn + (size_t)64 * DIMD, &nB[2048 + wave * 512]);
    }

    const bf16* sA = lA[kt & 1];
    const bf16* sB = lB[kt & 1];
    bf16x8 af[4], bfr[4];
#pragma unroll
    for (int i = 0; i < 4; i++)
      af[i] = *(const bf16x8*)&sA[(wm * 64 + i * 16 + l15) * 32 + quad * 8];
#pragma unroll
    for (int i = 0; i < 4; i++)
      bfr[i] = *(const bf16x8*)&sB[(wn * 64 + i * 16 + l15) * 32 + quad * 8];
#pragma unroll
    for (int i = 0; i < 4; i++)
#pragma unroll
      for (int j = 0; j < 4; j++)
        acc[i][j] = __builtin_amdgcn_mfma_f32_16x16x32_bf16(af[i], bfr[j], acc[i][j], 0, 0, 0);
  }

  const int sel = tn >> 10;  // 0=Q 1=K 2=V
#pragma unroll
  for (int j = 0; j < 4; j++) {
    const int n = tn + wn * 64 + j * 16 + l15;
    const float bv = bias[n];
    const int d = n & 1023, h = d >> 6, hd = d & 63;
#pragma unroll
    for (int i = 0; i < 4; i++) {
      const int mbase = tm + wm * 64 + i * 16 + quad * 4;
      const int b = mbase >> 11, s0 = mbase & 2047;
      const int bh = b * NHEAD + h;
      if (sel == 2) {
        bf16x4 vv = { (bf16)(acc[i][j][0] + bv), (bf16)(acc[i][j][1] + bv),
                      (bf16)(acc[i][j][2] + bv), (bf16)(acc[i][j][3] + bv) };
        *(bf16x4*)&Vt[((size_t)bh * HDIM + hd) * SEQ + s0] = vv;
      } else {
#pragma unroll
        for (int r = 0; r < 4; r++) {
          float v = acc[i][j][r] + bv;
          if (sel == 0)
            Qb[((size_t)bh * SEQ + s0 + r) * HDIM + hd] = (bf16)(v * 0.18033688f); // 0.125*log2e
          else
            Kb[((size_t)bh * SEQ + s0 + r) * HDIM + hd] = (bf16)v;
        }
      }
    }
  }
}

// ---------------- proj GEMM v2 (exact round-4 revert — g2l16 both) ----------
// v3 (f32 reg-stage B) cost ~10us vs this + 2us cvt: g2l16 wins. [R7 lesson]
__global__ __launch_bounds__(256, 2) void gemm_proj(
    const bf16* __restrict__ A, const bf16* __restrict__ Bt,
    const float* __restrict__ bias, float* __restrict__ out)
{
  __shared__ bf16 lA[2][64 * 32];
  __shared__ bf16 lB[2][128 * 32];
  const int tid = threadIdx.x;
  const int wave = tid >> 6, lane = tid & 63;
  const int l15 = lane & 15, quad = lane >> 4;
  const int tm = blockIdx.y * 64, tn = blockIdx.x * 128;

  f32x4 acc[4][2] = {};

  const int srow = tid >> 2, sch = (tid & 3) * 8;
  const bf16* ga = &A[(size_t)(tm + srow) * DIMD + sch];
  const bf16* gb = &Bt[(size_t)(tn + srow) * DIMD + sch];

  g2l16(ga,                     &lA[0][wave * 512]);
  g2l16(gb,                     &lB[0][wave * 512]);
  g2l16(gb + (size_t)64 * DIMD, &lB[0][2048 + wave * 512]);

  for (int kt = 0; kt < 32; kt++) {
    __syncthreads();

    if (kt < 31) {
      const int kn = (kt + 1) * 32;
      bf16* nA = lA[(kt + 1) & 1];
      bf16* nB = lB[(kt + 1) & 1];
      g2l16(ga + kn,                     &nA[wave * 512]);
      g2l16(gb + kn,                     &nB[wave * 512]);
      g2l16(gb + kn + (size_t)64 * DIMD, &nB[2048 + wave * 512]);
    }

    const bf16* sA = lA[kt & 1];
    const bf16* sB = lB[kt & 1];
    bf16x8 af[4], bfr[2];
#pragma unroll
    for (int i = 0; i < 4; i++)
      af[i] = *(const bf16x8*)&sA[(i * 16 + l15) * 32 + quad * 8];
#pragma unroll
    for (int j = 0; j < 2; j++)
      bfr[j] = *(const bf16x8*)&sB[(wave * 32 + j * 16 + l15) * 32 + quad * 8];
#pragma unroll
    for (int i = 0; i < 4; i++)
#pragma unroll
      for (int j = 0; j < 2; j++)
        acc[i][j] = __builtin_amdgcn_mfma_f32_16x16x32_bf16(af[i], bfr[j], acc[i][j], 0, 0, 0);
  }

#pragma unroll
  for (int j = 0; j < 2; j++) {
    const int n = tn + wave * 32 + j * 16 + l15;
    const float bv = bias[n];
#pragma unroll
    for (int i = 0; i < 4; i++) {
      const int mbase = tm + i * 16 + quad * 4;
#pragma unroll
      for (int r = 0; r < 4; r++)
        out[(size_t)(mbase + r) * DIMD + n] = acc[i][j][r] + bv;
    }
  }
}

// ---------------- flash attention v10 (unchanged — 57.6us proven) -----------
#define LSTR 72
__global__ __launch_bounds__(256, 2) void attn_kernel(
    const bf16* __restrict__ Qb, const bf16* __restrict__ Kb,
    const bf16* __restrict__ Vt, bf16* __restrict__ Ob)
{
  __shared__ bf16 lKV[2][2][64 * LSTR];   // [buf][K=0/V=1]

  const int tid = threadIdx.x;
  const int wave = tid >> 6, lane = tid & 63;
  const int l31 = lane & 31, h = lane >> 5;
  const int xcd = blockIdx.x & 7, grp = blockIdx.x >> 3;
  const int bh = xcd + 8 * (grp & 3);
  const int qt = grp >> 2;

  const int qrow = qt * 128 + wave * 32 + l31;
  const bf16* qp = Qb + ((size_t)bh * SEQ + qrow) * HDIM + h * 8;
  bf16x8 qf[4];
#pragma unroll
  for (int c = 0; c < 4; c++) qf[c] = *(const bf16x8*)(qp + c * 16);

  const int srow = tid >> 3;            // 0..31
  const int sch = (tid & 7) * 8;        // bf16 elem offset in 64
  const bf16* kg = Kb + ((size_t)bh * SEQ + srow) * HDIM + sch;
  const bf16* vg = Vt + ((size_t)bh * HDIM + srow) * SEQ + sch;

  uint4 kr0 = *(const uint4*)(kg);
  uint4 kr1 = *(const uint4*)(kg + 32 * HDIM);
  uint4 vr0 = *(const uint4*)(vg);
  uint4 vr1 = *(const uint4*)(vg + 32 * SEQ);

  bf16x8 pf[4];   // packed P(t-1)

  f32x16 o0 = {}, o1 = {};
  float mrow = -1e30f, lrow = 0.f;

  for (int kt = 0; kt < SEQ / 64; kt++) {
    bf16* sK = lKV[kt & 1][0];
    bf16* sV = lKV[kt & 1][1];
    *(uint4*)&sK[srow * LSTR + sch]        = kr0;
    *(uint4*)&sK[(32 + srow) * LSTR + sch] = kr1;
    *(uint4*)&sV[srow * LSTR + sch]        = vr0;
    *(uint4*)&sV[(32 + srow) * LSTR + sch] = vr1;
    __syncthreads();

    const int ktn = (kt + 1) & (SEQ / 64 - 1);
    kr0 = *(const uint4*)(kg + (size_t)ktn * 64 * HDIM);
    kr1 = *(const uint4*)(kg + (size_t)ktn * 64 * HDIM + 32 * HDIM);
    vr0 = *(const uint4*)(vg + ktn * 64);
    vr1 = *(const uint4*)(vg + ktn * 64 + 32 * SEQ);

    // S^T(t) = K Q^T
    f32x16 s0 = {}, s1 = {};
#pragma unroll
    for (int c = 0; c < 4; c++) {
      bf16x8 k0 = *(const bf16x8*)&sK[l31 * LSTR + c * 16 + h * 8];
      bf16x8 k1 = *(const bf16x8*)&sK[(32 + l31) * LSTR + c * 16 + h * 8];
      s0 = __builtin_amdgcn_mfma_f32_32x32x16_bf16(k0, qf[c], s0, 0, 0, 0);
      s1 = __builtin_amdgcn_mfma_f32_32x32x16_bf16(k1, qf[c], s1, 0, 0, 0);
    }

    // PV(t-1): P in pf regs, V(t-1) in the OTHER KV buffer.
    if (kt > 0) {
      const bf16* pV = lKV[(kt + 1) & 1][1];
#pragma unroll
      for (int c = 0; c < 4; c++) {
        bf16x8 v0 = *(const bf16x8*)&pV[l31 * LSTR + c * 16 + h * 8];
        bf16x8 v1 = *(const bf16x8*)&pV[(32 + l31) * LSTR + c * 16 + h * 8];
        o0 = __builtin_amdgcn_mfma_f32_32x32x16_bf16(v0, pf[c], o0, 0, 0, 0);
        o1 = __builtin_amdgcn_mfma_f32_32x32x16_bf16(v1, pf[c], o1, 0, 0, 0);
      }
    }

    // softmax(t)
    float mx = -1e30f;
#pragma unroll
    for (int r = 0; r < 16; r++) { mx = fmaxf(mx, s0[r]); mx = fmaxf(mx, s1[r]); }
    mx = fmaxf(mx, __shfl_xor(mx, 32, 64));
    const float nm = fmaxf(mrow, mx);
    const float alpha = EXP2F(mrow - nm);
    mrow = nm;

    float rs = 0.f;
#pragma unroll
    for (int r = 0; r < 16; r++) {
      const float p0 = EXP2F(s0[r] - nm);
      const float p1 = EXP2F(s1[r] - nm);
      s0[r] = p0; s1[r] = p1;
      rs += p0 + p1;
    }
    rs += __shfl_xor(rs, 32, 64);
    lrow = lrow * alpha + rs;

#pragma unroll
    for (int r = 0; r < 16; r++) { o0[r] *= alpha; o1[r] *= alpha; }

    // pack P(t) -> pf regs via half-exchange
#pragma unroll
    for (int g = 0; g < 2; g++) {
      const f32x16& sg = (g == 0) ? s0 : s1;
#pragma unroll
      for (int cp = 0; cp < 2; cp++) {
        bf16x4 pk0 = { (bf16)sg[8 * cp + 0], (bf16)sg[8 * cp + 1],
                       (bf16)sg[8 * cp + 2], (bf16)sg[8 * cp + 3] };   // q=2cp
        bf16x4 pk1 = { (bf16)sg[8 * cp + 4], (bf16)sg[8 * cp + 5],
                       (bf16)sg[8 * cp + 6], (bf16)sg[8 * cp + 7] };   // q=2cp+1
        uint2 w0 = *(uint2*)&pk0;
        uint2 w1 = *(uint2*)&pk1;
        unsigned send0 = h ? w0.x : w1.x;
        unsigned send1 = h ? w0.y : w1.y;
        unsigned recv0 = __shfl_xor(send0, 32, 64);
        unsigned recv1 = __shfl_xor(send1, 32, 64);
        union { unsigned u[4]; bf16x8 v; } f;
        f.u[0] = h ? recv0 : w0.x;
        f.u[1] = h ? recv1 : w0.y;
        f.u[2] = h ? w1.x : recv0;
        f.u[3] = h ? w1.y : recv1;
        pf[2 * g + cp] = f.v;
      }
    }
  }

  // drain: PV(31)
  {
    const bf16* pV = lKV[1][1];
#pragma unroll
    for (int c = 0; c < 4; c++) {
      bf16x8 v0 = *(const bf16x8*)&pV[l31 * LSTR + c * 16 + h * 8];
      bf16x8 v1 = *(const bf16x8*)&pV[(32 + l31) * LSTR + c * 16 + h * 8];
      o0 = __builtin_amdgcn_mfma_f32_32x32x16_bf16(v0, pf[c], o0, 0, 0, 0);
      o1 = __builtin_amdgcn_mfma_f32_32x32x16_bf16(v1, pf[c], o1, 0, 0, 0);
    }
  }

  const int b = bh >> 4, head = bh & 15;
  const float inv = 1.f / lrow;
  const size_t base = ((size_t)b * SEQ + qrow) * DIMD + head * HDIM;
#pragma unroll
  for (int g = 0; g < 4; g++) {
    bf16x4 oa = { (bf16)(o0[4*g] * inv), (bf16)(o0[4*g+1] * inv),
                  (bf16)(o0[4*g+2] * inv), (bf16)(o0[4*g+3] * inv) };
    bf16x4 ob = { (bf16)(o1[4*g] * inv), (bf16)(o1[4*g+1] * inv),
                  (bf16)(o1[4*g+2] * inv), (bf16)(o1[4*g+3] * inv) };
    *(bf16x4*)&Ob[base + g * 8 + h * 4]      = oa;
    *(bf16x4*)&Ob[base + 32 + g * 8 + h * 4] = ob;
  }
}

extern "C" void kernel_launch(void* const* d_in, const int* in_sizes, int n_in,
                              void* d_out, int out_size, void* d_ws, size_t ws_size,
                              hipStream_t stream) {
  const float* x      = (const float*)d_in[0];
  const float* w_qkv  = (const float*)d_in[1];
  const float* b_qkv  = (const float*)d_in[2];
  const float* w_proj = (const float*)d_in[3];
  const float* b_proj = (const float*)d_in[4];
  float* out = (float*)d_out;
  char* ws = (char*)d_ws;

  bf16* Qb = (bf16*)d_out;
  bf16* Kb = (bf16*)d_out + (size_t)MTOT * DIMD;
  bf16* xb     = (bf16*)(ws + OFF_XB);
  bf16* Ob     = (bf16*)(ws + OFF_OB);   // overlays xb (dead after QKV GEMM)
  bf16* Vt     = (bf16*)(ws + OFF_VT);
  bf16* wprojb = (bf16*)(ws + OFF_WP);   // overlays Vt (dead after attn)
  bf16* wqkvb  = (bf16*)(ws + OFF_WQ);   // new 6MB region (ws ~= 256MiB)

  const int NCVT = (MTOT * DIMD / 4) + (3 * DIMD * DIMD / 4);
  cvt2_kernel<<<NCVT / 256, 256, 0, stream>>>(x, w_qkv, xb, wqkvb);
  gemm_qkv<<<dim3(24, 32), 256, 0, stream>>>(xb, wqkvb, b_qkv, Qb, Kb, Vt);
  attn_kernel<<<BATCH * NHEAD * (SEQ / 128), 256, 0, stream>>>(Qb, Kb, Vt, Ob);
  cvt_kernel<<<(DIMD * DIMD / 4) / 256, 256, 0, stream>>>(w_proj, wprojb, DIMD * DIMD / 4);
  gemm_proj<<<dim3(8, 64), 256, 0, stream>>>(Ob, wprojb, b_proj, out);
}